// Round 1
// baseline (959.408 us; speedup 1.0000x reference)
//
#include <hip/hip_runtime.h>

// B=256, F=16, FO=32, J=22, H=8, IN=256, OUT=512, HID=64, HS=32
// Degenerate-einsum analysis:
//   attn_s = qsum (x) ksum  (outer product of channel sums)
//   x_s    = diag(softmax(attn_s)) * (sum_u v_s')
//   x_t    = sum_f v_t  (softmax sums to 1; q_t/k_t/conv_t/mask_t unused)

#define NEGV (-1000000000.0f)

// ---------------- prep: pre-summed weight columns ----------------
// sqw[i][m] = sum_{c=0..31} Wq_w[i][m*64+c]   (q_s takes first 32 of each 64-chunk)
__global__ void prep_kernel(const float* __restrict__ Wq_w, const float* __restrict__ Wq_b,
                            const float* __restrict__ Wk_w, const float* __restrict__ Wk_b,
                            float* __restrict__ sqw, float* __restrict__ sqb,
                            float* __restrict__ skw, float* __restrict__ skb) {
  int i = threadIdx.x;  // 0..255
  for (int m = 0; m < 8; ++m) {
    float aq = 0.f, ak = 0.f;
    #pragma unroll
    for (int c = 0; c < 32; ++c) {
      aq += Wq_w[i * 512 + m * 64 + c];
      ak += Wk_w[i * 512 + m * 64 + c];
    }
    sqw[i * 8 + m] = aq;
    skw[i * 8 + m] = ak;
  }
  if (i < 8) {
    float aq = 0.f, ak = 0.f;
    for (int c = 0; c < 32; ++c) { aq += Wq_b[i * 64 + c]; ak += Wk_b[i * 64 + c]; }
    sqb[i] = aq;
    skb[i] = ak;
  }
}

// ---------------- qsum[b][h][t][s] = sum_c q_s ----------------
// one block per (b, fo2) input row-slab; each row yields 8 scattered outputs
__global__ __launch_bounds__(256) void qsum_kernel(const float* __restrict__ q,
                                                   const float* __restrict__ sqw,
                                                   const float* __restrict__ sqb,
                                                   float* __restrict__ qsum) {
  int blk = blockIdx.x;  // b*32 + fo2
  int fo2 = blk & 31;
  int b = blk >> 5;
  __shared__ float lq[22][257];
  __shared__ float lw[2048];
  __shared__ float lb[8];
  int tid = threadIdx.x;
  const float* qb = q + (size_t)blk * (22 * 256);
  #pragma unroll
  for (int j = 0; j < 22; ++j) lq[j][tid] = qb[j * 256 + tid];
  for (int r = tid; r < 2048; r += 256) lw[r] = sqw[r];
  if (tid < 8) lb[tid] = sqb[tid];
  __syncthreads();
  if (tid < 176) {
    int j2 = tid >> 3, m = tid & 7;
    float acc = lb[m];
    for (int i = 0; i < 256; ++i) acc += lq[j2][i] * lw[i * 8 + m];
    int lf = (fo2 & 3) * 11264 + j2 * 512 + m * 64;  // local flat within head chunk
    int t = lf / 1408;
    int s = (lf % 1408) >> 6;
    int h = fo2 >> 2;
    qsum[(((size_t)b * 8 + h) * 32 + t) * 22 + s] = acc;
  }
}

// ---------------- ksumraw[b][h][f][j] = sum_d k_s ----------------
__global__ __launch_bounds__(256) void ksum_kernel(const float* __restrict__ k,
                                                   const float* __restrict__ skw,
                                                   const float* __restrict__ skb,
                                                   float* __restrict__ ksumraw) {
  int blk = blockIdx.x;  // b*16 + f2
  int f2 = blk & 15;
  int b = blk >> 4;
  __shared__ float lk[22][257];
  __shared__ float lw[2048];
  __shared__ float lb[8];
  int tid = threadIdx.x;
  const float* kb = k + (size_t)blk * (22 * 256);
  #pragma unroll
  for (int j = 0; j < 22; ++j) lk[j][tid] = kb[j * 256 + tid];
  for (int r = tid; r < 2048; r += 256) lw[r] = skw[r];
  if (tid < 8) lb[tid] = skb[tid];
  __syncthreads();
  if (tid < 176) {
    int j2 = tid >> 3, m = tid & 7;
    float acc = lb[m];
    for (int i = 0; i < 256; ++i) acc += lk[j2][i] * lw[i * 8 + m];
    int lf = (f2 & 1) * 11264 + j2 * 512 + m * 64;  // local flat within head chunk (22528)
    int floc = lf / 1408;
    int j = (lf % 1408) >> 6;
    int h = f2 >> 1;
    ksumraw[(((size_t)b * 8 + h) * 16 + floc) * 22 + j] = acc;
  }
}

// ---------------- ksum_s[b][h][o][j] = conv_s over ksumraw ----------------
__global__ void convk_kernel(const float* __restrict__ ksumraw, const float* __restrict__ csw,
                             const float* __restrict__ csb, float* __restrict__ ksum_s) {
  size_t idx = (size_t)blockIdx.x * 256 + threadIdx.x;  // 256*8*32*22
  if (idx >= (size_t)256 * 8 * 32 * 22) return;
  int j = (int)(idx % 22);
  size_t r = idx / 22;
  int o = (int)(r % 32);
  size_t bh = r / 32;
  float acc = 32.0f * csb[o];
  #pragma unroll
  for (int f = 0; f < 16; ++f) acc += csw[o * 16 + f] * ksumraw[(bh * 16 + f) * 22 + j];
  ksum_s[idx] = acc;
}

// ---------------- V projection + scatter-reduce ----------------
// block per (b,h): GEMM 44x512x256 (rows in LDS, one column per thread),
// reduce first-half channels over u -> vs_inner[b][h][f][32],
// second-half channels over f -> vtsum[b][h][j][32].
__global__ __launch_bounds__(512) void vproj_kernel(const float* __restrict__ v,
                                                    const float* __restrict__ Wv,
                                                    const float* __restrict__ Wv_b,
                                                    float* __restrict__ vs_inner,
                                                    float* __restrict__ vtsum) {
  int bh = blockIdx.x;
  __shared__ float lv[44][256];
  __shared__ float vs_acc[512];  // [f][d<32]
  __shared__ float vt_acc[704];  // [j][g]
  int tid = threadIdx.x;  // 0..511
  // rows f2 = 2h, 2h+1 are contiguous: 44 rows of 256
  const float* vb = v + (size_t)bh * (2 * 22 * 256);
  float* lvf = &lv[0][0];
  for (int r = tid; r < 44 * 256; r += 512) lvf[r] = vb[r];
  if (tid < 512) vs_acc[tid] = 0.f;
  for (int r = tid; r < 704; r += 512) vt_acc[r] = 0.f;
  __syncthreads();

  int c = tid;
  float bias = Wv_b[c];
  float acc[44];
  #pragma unroll
  for (int r = 0; r < 44; ++r) acc[r] = 0.f;

  for (int i0 = 0; i0 < 256; i0 += 8) {
    float w[8];
    #pragma unroll
    for (int qq = 0; qq < 8; ++qq) w[qq] = Wv[(size_t)(i0 + qq) * 512 + c];
    #pragma unroll
    for (int r = 0; r < 44; ++r) {
      const float4* p = reinterpret_cast<const float4*>(&lv[r][i0]);
      float4 x0 = p[0];
      float4 x1 = p[1];
      acc[r] += x0.x * w[0] + x0.y * w[1] + x0.z * w[2] + x0.w * w[3] +
                x1.x * w[4] + x1.y * w[5] + x1.z * w[6] + x1.w * w[7];
    }
  }

  int c6 = c >> 6, d = c & 63;
  #pragma unroll
  for (int r = 0; r < 44; ++r) {
    int f2loc = r / 22, j2 = r % 22;
    int fj = f2loc * 176 + j2 * 8 + c6;  // = local_flat/64
    int f = fj / 22, j = fj % 22;
    float val = acc[r] + bias;
    if (d < 32)
      atomicAdd(&vs_acc[f * 32 + d], val);     // sum over u(=j)
    else
      atomicAdd(&vt_acc[j * 32 + (d - 32)], val);  // sum over f
  }
  __syncthreads();
  float* vsg = vs_inner + (size_t)bh * 512;
  float* vtg = vtsum + (size_t)bh * 704;
  if (tid < 512) vsg[tid] = vs_acc[tid];
  for (int r = tid; r < 704; r += 512) vtg[r] = vt_acc[r];
}

// ---------------- vssum[b][h][t][d] = conv_s over vs_inner ----------------
__global__ void convv_kernel(const float* __restrict__ vs_inner, const float* __restrict__ csw,
                             const float* __restrict__ csb, float* __restrict__ vssum) {
  size_t idx = (size_t)blockIdx.x * 256 + threadIdx.x;  // 256*8*32*32
  if (idx >= (size_t)256 * 8 * 32 * 32) return;
  int d = (int)(idx & 31);
  size_t r = idx >> 5;
  int t = (int)(r & 31);
  size_t bh = r >> 5;
  float acc = 22.0f * csb[t];
  #pragma unroll
  for (int f = 0; f < 16; ++f) acc += csw[t * 16 + f] * vs_inner[(bh * 16 + f) * 32 + d];
  vssum[idx] = acc;
}

// ---------------- final: diag softmax + assemble output ----------------
__global__ __launch_bounds__(256) void final_kernel(const float* __restrict__ qsum,
                                                    const float* __restrict__ ksum_s,
                                                    const float* __restrict__ vssum,
                                                    const float* __restrict__ vtsum,
                                                    const int* __restrict__ mask_s,
                                                    float* __restrict__ out) {
  int blk = blockIdx.x;  // b*32 + t
  int t = blk & 31;
  int b = blk >> 5;
  __shared__ float ql[8][22], kl[8][22], vsl[8][32], dg[8][22];
  __shared__ float vtl[8][704];
  __shared__ int msk[484];
  int tid = threadIdx.x;
  size_t bbase = (size_t)b * 8;
  if (tid < 176) {
    int h = tid / 22, s = tid % 22;
    ql[h][s] = qsum[((bbase + h) * 32 + t) * 22 + s];
    kl[h][s] = ksum_s[((bbase + h) * 32 + t) * 22 + s];
  }
  {
    int h = tid >> 5, d = tid & 31;
    vsl[h][d] = vssum[((bbase + h) * 32 + t) * 32 + d];
  }
  for (int idx = tid; idx < 5632; idx += 256) {
    int h = idx / 704, r = idx % 704;
    vtl[h][r] = vtsum[(bbase + h) * 704 + r];
  }
  for (int idx = tid; idx < 484; idx += 256) msk[idx] = mask_s[idx];
  __syncthreads();
  if (tid < 176) {
    int h = tid / 22, s = tid % 22;
    float qv = ql[h][s];
    float mx = -3.0e38f;
    #pragma unroll
    for (int u = 0; u < 22; ++u) {
      float av = msk[s * 22 + u] ? qv * kl[h][u] : NEGV;
      mx = fmaxf(mx, av);
    }
    float den = 0.f;
    #pragma unroll
    for (int u = 0; u < 22; ++u) {
      float av = msk[s * 22 + u] ? qv * kl[h][u] : NEGV;
      den += expf(av - mx);
    }
    float as = msk[s * 22 + s] ? qv * kl[h][s] : NEGV;
    dg[h][s] = expf(as - mx) / den;
  }
  __syncthreads();
  float* ob = out + (size_t)blk * (22 * 512);
  for (int idx = tid; idx < 11264; idx += 256) {
    int s = idx >> 9;
    int ch = idx & 511;
    int h = ch >> 6;
    int d = ch & 63;
    float val = (d < 32) ? dg[h][s] * vsl[h][d] : vtl[h][s * 32 + (d & 31)];
    ob[idx] = val;
  }
}

extern "C" void kernel_launch(void* const* d_in, const int* in_sizes, int n_in,
                              void* d_out, int out_size, void* d_ws, size_t ws_size,
                              hipStream_t stream) {
  const float* q = (const float*)d_in[0];
  const float* k = (const float*)d_in[1];
  const float* v = (const float*)d_in[2];
  const int* mask_s = (const int*)d_in[3];
  // d_in[4] mask_t: unused (softmax over attn_t sums to 1)
  const float* Wq_w = (const float*)d_in[5];
  const float* Wq_b = (const float*)d_in[6];
  const float* Wk_w = (const float*)d_in[7];
  const float* Wk_b = (const float*)d_in[8];
  const float* Wv_w = (const float*)d_in[9];
  const float* Wv_b = (const float*)d_in[10];
  const float* csw = (const float*)d_in[11];
  const float* csb = (const float*)d_in[12];
  // d_in[13], d_in[14] conv_t_*: unused
  float* out = (float*)d_out;

  float* ws = (float*)d_ws;
  float* sqw = ws;                         // 2048
  float* sqb = sqw + 2048;                 // 8
  float* skw = sqb + 8;                    // 2048
  float* skb = skw + 2048;                 // 8
  float* qsum = skb + 8;                   // 256*8*32*22 = 1441792
  float* ksumraw = qsum + 1441792;         // 256*8*16*22 = 720896
  float* ksum_s = ksumraw + 720896;        // 1441792
  float* vs_inner = ksum_s + 1441792;      // 256*8*16*32 = 1048576
  float* vtsum = vs_inner + 1048576;       // 256*8*22*32 = 1441792
  float* vssum = vtsum + 1441792;          // 256*8*32*32 = 2097152

  hipLaunchKernelGGL(prep_kernel, dim3(1), dim3(256), 0, stream,
                     Wq_w, Wq_b, Wk_w, Wk_b, sqw, sqb, skw, skb);
  hipLaunchKernelGGL(qsum_kernel, dim3(256 * 32), dim3(256), 0, stream, q, sqw, sqb, qsum);
  hipLaunchKernelGGL(ksum_kernel, dim3(256 * 16), dim3(256), 0, stream, k, skw, skb, ksumraw);
  hipLaunchKernelGGL(convk_kernel, dim3(5632), dim3(256), 0, stream, ksumraw, csw, csb, ksum_s);
  hipLaunchKernelGGL(vproj_kernel, dim3(2048), dim3(512), 0, stream, v, Wv_w, Wv_b, vs_inner, vtsum);
  hipLaunchKernelGGL(convv_kernel, dim3(8192), dim3(256), 0, stream, vs_inner, csw, csb, vssum);
  hipLaunchKernelGGL(final_kernel, dim3(8192), dim3(256), 0, stream,
                     qsum, ksum_s, vssum, vtsum, mask_s, out);
}

// Round 2
// 556.669 us; speedup vs baseline: 1.7235x; 1.7235x over previous
//
#include <hip/hip_runtime.h>

// B=256, F=16, FO=32, J=22, H=8, IN=256, OUT=512, HID=64, HS=32
// Degenerate-einsum analysis:
//   attn_s = qsum (x) ksum  (outer product of channel sums)
//   x_s    = diag(softmax(attn_s)) * (sum_u v_s')
//   x_t    = sum_f v_t  (softmax sums to 1; q_t/k_t/conv_t/mask_t unused)
// Round 1: vproj -> bf16 MFMA (16x16x32), A staged bf16 in LDS, B from
// pre-transposed bf16 Wv in global (L2-hot), f32 accum, LDS scatter-reduce.

#define NEGV (-1000000000.0f)

typedef __attribute__((ext_vector_type(8))) short short8;
typedef __attribute__((ext_vector_type(4))) float f32x4;

__device__ inline ushort f2bf(float f) {
  union { float f; unsigned u; } a;
  a.f = f;
  unsigned u = a.u;
  return (ushort)((u + 0x7FFFu + ((u >> 16) & 1u)) >> 16);  // RNE
}

// ---------------- prep: pre-summed weight columns ----------------
__global__ void prep_kernel(const float* __restrict__ Wq_w, const float* __restrict__ Wq_b,
                            const float* __restrict__ Wk_w, const float* __restrict__ Wk_b,
                            float* __restrict__ sqw, float* __restrict__ sqb,
                            float* __restrict__ skw, float* __restrict__ skb) {
  int i = threadIdx.x;  // 0..255
  for (int m = 0; m < 8; ++m) {
    float aq = 0.f, ak = 0.f;
    #pragma unroll
    for (int c = 0; c < 32; ++c) {
      aq += Wq_w[i * 512 + m * 64 + c];
      ak += Wk_w[i * 512 + m * 64 + c];
    }
    sqw[i * 8 + m] = aq;
    skw[i * 8 + m] = ak;
  }
  if (i < 8) {
    float aq = 0.f, ak = 0.f;
    for (int c = 0; c < 32; ++c) { aq += Wq_b[i * 64 + c]; ak += Wk_b[i * 64 + c]; }
    sqb[i] = aq;
    skb[i] = ak;
  }
}

// ---------------- Wv -> bf16 transposed [512][256] ----------------
__global__ void wvt_kernel(const float* __restrict__ Wv, ushort* __restrict__ wvt) {
  int i = blockIdx.x;   // k: 0..255
  int c = threadIdx.x;  // col: 0..511
  wvt[(size_t)c * 256 + i] = f2bf(Wv[(size_t)i * 512 + c]);
}

// ---------------- qsum[b][h][t][s] = sum_c q_s ----------------
__global__ __launch_bounds__(256) void qsum_kernel(const float* __restrict__ q,
                                                   const float* __restrict__ sqw,
                                                   const float* __restrict__ sqb,
                                                   float* __restrict__ qsum) {
  int blk = blockIdx.x;  // b*32 + fo2
  int fo2 = blk & 31;
  int b = blk >> 5;
  __shared__ float lq[22][257];
  __shared__ float lw[2048];
  __shared__ float lb[8];
  int tid = threadIdx.x;
  const float* qb = q + (size_t)blk * (22 * 256);
  #pragma unroll
  for (int j = 0; j < 22; ++j) lq[j][tid] = qb[j * 256 + tid];
  for (int r = tid; r < 2048; r += 256) lw[r] = sqw[r];
  if (tid < 8) lb[tid] = sqb[tid];
  __syncthreads();
  if (tid < 176) {
    int j2 = tid >> 3, m = tid & 7;
    float acc = lb[m];
    for (int i = 0; i < 256; ++i) acc += lq[j2][i] * lw[i * 8 + m];
    int lf = (fo2 & 3) * 11264 + j2 * 512 + m * 64;
    int t = lf / 1408;
    int s = (lf % 1408) >> 6;
    int h = fo2 >> 2;
    qsum[(((size_t)b * 8 + h) * 32 + t) * 22 + s] = acc;
  }
}

// ---------------- ksumraw[b][h][f][j] = sum_d k_s ----------------
__global__ __launch_bounds__(256) void ksum_kernel(const float* __restrict__ k,
                                                   const float* __restrict__ skw,
                                                   const float* __restrict__ skb,
                                                   float* __restrict__ ksumraw) {
  int blk = blockIdx.x;  // b*16 + f2
  int f2 = blk & 15;
  int b = blk >> 4;
  __shared__ float lk[22][257];
  __shared__ float lw[2048];
  __shared__ float lb[8];
  int tid = threadIdx.x;
  const float* kb = k + (size_t)blk * (22 * 256);
  #pragma unroll
  for (int j = 0; j < 22; ++j) lk[j][tid] = kb[j * 256 + tid];
  for (int r = tid; r < 2048; r += 256) lw[r] = skw[r];
  if (tid < 8) lb[tid] = skb[tid];
  __syncthreads();
  if (tid < 176) {
    int j2 = tid >> 3, m = tid & 7;
    float acc = lb[m];
    for (int i = 0; i < 256; ++i) acc += lk[j2][i] * lw[i * 8 + m];
    int lf = (f2 & 1) * 11264 + j2 * 512 + m * 64;
    int floc = lf / 1408;
    int j = (lf % 1408) >> 6;
    int h = f2 >> 1;
    ksumraw[(((size_t)b * 8 + h) * 16 + floc) * 22 + j] = acc;
  }
}

// ---------------- ksum_s = conv_s over ksumraw ----------------
__global__ void convk_kernel(const float* __restrict__ ksumraw, const float* __restrict__ csw,
                             const float* __restrict__ csb, float* __restrict__ ksum_s) {
  size_t idx = (size_t)blockIdx.x * 256 + threadIdx.x;
  if (idx >= (size_t)256 * 8 * 32 * 22) return;
  int j = (int)(idx % 22);
  size_t r = idx / 22;
  int o = (int)(r % 32);
  size_t bh = r / 32;
  float acc = 32.0f * csb[o];
  #pragma unroll
  for (int f = 0; f < 16; ++f) acc += csw[o * 16 + f] * ksumraw[(bh * 16 + f) * 22 + j];
  ksum_s[idx] = acc;
}

// ---------------- V projection via MFMA + scatter-reduce ----------------
// Block per (b,h): A = 44x256 rows (bf16 in LDS, padded to 48),
// B = wvt[512][256] bf16 from global (L2-hot). D = 44x512 f32, scattered
// into vs_acc[16][32] (sum over j') and vt_acc[22][32] (sum over f').
__global__ __launch_bounds__(256) void vproj_mfma_kernel(const float* __restrict__ v,
                                                         const ushort* __restrict__ wvt,
                                                         const float* __restrict__ Wv_b,
                                                         float* __restrict__ vs_inner,
                                                         float* __restrict__ vtsum) {
  int bh = blockIdx.x;
  __shared__ ushort lA[48 * 256];
  __shared__ float vs_acc[512];
  __shared__ float vt_acc[704];
  int tid = threadIdx.x;

  // stage A: 44x256 f32 -> bf16
  const float4* vb4 = reinterpret_cast<const float4*>(v + (size_t)bh * (44 * 256));
  #pragma unroll
  for (int it = 0; it < 11; ++it) {
    int idx = tid + it * 256;  // float4 index, 2816 total
    float4 x = vb4[idx];
    ushort4 u;
    u.x = f2bf(x.x);
    u.y = f2bf(x.y);
    u.z = f2bf(x.z);
    u.w = f2bf(x.w);
    *reinterpret_cast<ushort4*>(&lA[idx * 4]) = u;
  }
  {  // zero pad rows 44..47
    ushort4 z = {0, 0, 0, 0};
    *reinterpret_cast<ushort4*>(&lA[11264 + tid * 4]) = z;
  }
  vs_acc[tid] = 0.f;
  vs_acc[tid + 256] = 0.f;
  for (int r = tid; r < 704; r += 256) vt_acc[r] = 0.f;
  __syncthreads();

  int lane = tid & 63, wid = tid >> 6;
  int r0 = lane & 15, kb = lane >> 4;

  // preload all A fragments: 3 M-tiles x 8 K-steps
  short8 afrag[3][8];
  #pragma unroll
  for (int m = 0; m < 3; ++m)
    #pragma unroll
    for (int ks = 0; ks < 8; ++ks)
      afrag[m][ks] = *reinterpret_cast<const short8*>(&lA[(m * 16 + r0) * 256 + ks * 32 + kb * 8]);

  for (int nt8 = 0; nt8 < 8; ++nt8) {
    int nt = wid * 8 + nt8;           // n-tile 0..31
    int ch = nt * 16 + r0;            // output column 0..511
    const ushort* bcol = wvt + (size_t)ch * 256 + kb * 8;
    f32x4 acc0 = {0.f, 0.f, 0.f, 0.f};
    f32x4 acc1 = {0.f, 0.f, 0.f, 0.f};
    f32x4 acc2 = {0.f, 0.f, 0.f, 0.f};
    #pragma unroll
    for (int ks = 0; ks < 8; ++ks) {
      short8 bfrag = *reinterpret_cast<const short8*>(bcol + ks * 32);
      acc0 = __builtin_amdgcn_mfma_f32_16x16x32_bf16(afrag[0][ks], bfrag, acc0, 0, 0, 0);
      acc1 = __builtin_amdgcn_mfma_f32_16x16x32_bf16(afrag[1][ks], bfrag, acc1, 0, 0, 0);
      acc2 = __builtin_amdgcn_mfma_f32_16x16x32_bf16(afrag[2][ks], bfrag, acc2, 0, 0, 0);
    }
    float bias = Wv_b[ch];
    int c6 = ch >> 6, d = ch & 63;
    #pragma unroll
    for (int m = 0; m < 3; ++m) {
      f32x4 acc = (m == 0) ? acc0 : ((m == 1) ? acc1 : acc2);
      #pragma unroll
      for (int reg = 0; reg < 4; ++reg) {
        int gr = m * 16 + kb * 4 + reg;  // D row = (lane>>4)*4 + reg (m89-verified)
        if (gr >= 44) continue;
        int f2loc = (gr >= 22) ? 1 : 0;
        int j = gr - f2loc * 22;
        int fj = f2loc * 176 + j * 8 + c6;  // output (f', j') flat
        int f = fj / 22;
        int jj = fj - f * 22;
        float val = acc[reg] + bias;
        if (d < 32)
          atomicAdd(&vs_acc[f * 32 + d], val);
        else
          atomicAdd(&vt_acc[jj * 32 + (d - 32)], val);
      }
    }
  }
  __syncthreads();
  float* vsg = vs_inner + (size_t)bh * 512;
  float* vtg = vtsum + (size_t)bh * 704;
  vsg[tid] = vs_acc[tid];
  vsg[tid + 256] = vs_acc[tid + 256];
  for (int r = tid; r < 704; r += 256) vtg[r] = vt_acc[r];
}

// ---------------- vssum = conv_s over vs_inner ----------------
__global__ void convv_kernel(const float* __restrict__ vs_inner, const float* __restrict__ csw,
                             const float* __restrict__ csb, float* __restrict__ vssum) {
  size_t idx = (size_t)blockIdx.x * 256 + threadIdx.x;
  if (idx >= (size_t)256 * 8 * 32 * 32) return;
  int d = (int)(idx & 31);
  size_t r = idx >> 5;
  int t = (int)(r & 31);
  size_t bh = r >> 5;
  float acc = 22.0f * csb[t];
  #pragma unroll
  for (int f = 0; f < 16; ++f) acc += csw[t * 16 + f] * vs_inner[(bh * 16 + f) * 32 + d];
  vssum[idx] = acc;
}

// ---------------- final: diag softmax + assemble output ----------------
__global__ __launch_bounds__(256) void final_kernel(const float* __restrict__ qsum,
                                                    const float* __restrict__ ksum_s,
                                                    const float* __restrict__ vssum,
                                                    const float* __restrict__ vtsum,
                                                    const int* __restrict__ mask_s,
                                                    float* __restrict__ out) {
  int blk = blockIdx.x;  // b*32 + t
  int t = blk & 31;
  int b = blk >> 5;
  __shared__ float ql[8][22], kl[8][22], vsl[8][32], dg[8][22];
  __shared__ float vtl[8][704];
  __shared__ int msk[484];
  int tid = threadIdx.x;
  size_t bbase = (size_t)b * 8;
  if (tid < 176) {
    int h = tid / 22, s = tid % 22;
    ql[h][s] = qsum[((bbase + h) * 32 + t) * 22 + s];
    kl[h][s] = ksum_s[((bbase + h) * 32 + t) * 22 + s];
  }
  {
    int h = tid >> 5, d = tid & 31;
    vsl[h][d] = vssum[((bbase + h) * 32 + t) * 32 + d];
  }
  for (int idx = tid; idx < 5632; idx += 256) {
    int h = idx / 704, r = idx % 704;
    vtl[h][r] = vtsum[(bbase + h) * 704 + r];
  }
  for (int idx = tid; idx < 484; idx += 256) msk[idx] = mask_s[idx];
  __syncthreads();
  if (tid < 176) {
    int h = tid / 22, s = tid % 22;
    float qv = ql[h][s];
    float mx = -3.0e38f;
    #pragma unroll
    for (int u = 0; u < 22; ++u) {
      float av = msk[s * 22 + u] ? qv * kl[h][u] : NEGV;
      mx = fmaxf(mx, av);
    }
    float den = 0.f;
    #pragma unroll
    for (int u = 0; u < 22; ++u) {
      float av = msk[s * 22 + u] ? qv * kl[h][u] : NEGV;
      den += expf(av - mx);
    }
    float as = msk[s * 22 + s] ? qv * kl[h][s] : NEGV;
    dg[h][s] = expf(as - mx) / den;
  }
  __syncthreads();
  float* ob = out + (size_t)blk * (22 * 512);
  for (int idx = tid; idx < 11264; idx += 256) {
    int s = idx >> 9;
    int ch = idx & 511;
    int h = ch >> 6;
    int d = ch & 63;
    float val = (d < 32) ? dg[h][s] * vsl[h][d] : vtl[h][s * 32 + (d & 31)];
    ob[idx] = val;
  }
}

extern "C" void kernel_launch(void* const* d_in, const int* in_sizes, int n_in,
                              void* d_out, int out_size, void* d_ws, size_t ws_size,
                              hipStream_t stream) {
  const float* q = (const float*)d_in[0];
  const float* k = (const float*)d_in[1];
  const float* v = (const float*)d_in[2];
  const int* mask_s = (const int*)d_in[3];
  const float* Wq_w = (const float*)d_in[5];
  const float* Wq_b = (const float*)d_in[6];
  const float* Wk_w = (const float*)d_in[7];
  const float* Wk_b = (const float*)d_in[8];
  const float* Wv_w = (const float*)d_in[9];
  const float* Wv_b = (const float*)d_in[10];
  const float* csw = (const float*)d_in[11];
  const float* csb = (const float*)d_in[12];
  float* out = (float*)d_out;

  float* ws = (float*)d_ws;
  float* sqw = ws;                         // 2048
  float* sqb = sqw + 2048;                 // 8
  float* skw = sqb + 8;                    // 2048
  float* skb = skw + 2048;                 // 8
  ushort* wvt = (ushort*)(skb + 8);        // 131072 ushorts (16B-aligned: float off 4112)
  float* qsum = (float*)(wvt + 131072);    // 1441792
  float* ksumraw = qsum + 1441792;         // 720896
  float* ksum_s = ksumraw + 720896;        // 1441792
  float* vs_inner = ksum_s + 1441792;      // 1048576
  float* vtsum = vs_inner + 1048576;       // 1441792
  float* vssum = vtsum + 1441792;          // 2097152

  hipLaunchKernelGGL(prep_kernel, dim3(1), dim3(256), 0, stream,
                     Wq_w, Wq_b, Wk_w, Wk_b, sqw, sqb, skw, skb);
  hipLaunchKernelGGL(wvt_kernel, dim3(256), dim3(512), 0, stream, Wv_w, wvt);
  hipLaunchKernelGGL(qsum_kernel, dim3(256 * 32), dim3(256), 0, stream, q, sqw, sqb, qsum);
  hipLaunchKernelGGL(ksum_kernel, dim3(256 * 16), dim3(256), 0, stream, k, skw, skb, ksumraw);
  hipLaunchKernelGGL(convk_kernel, dim3(5632), dim3(256), 0, stream, ksumraw, csw, csb, ksum_s);
  hipLaunchKernelGGL(vproj_mfma_kernel, dim3(2048), dim3(256), 0, stream,
                     v, wvt, Wv_b, vs_inner, vtsum);
  hipLaunchKernelGGL(convv_kernel, dim3(8192), dim3(256), 0, stream, vs_inner, csw, csb, vssum);
  hipLaunchKernelGGL(final_kernel, dim3(8192), dim3(256), 0, stream,
                     qsum, ksum_s, vssum, vtsum, mask_s, out);
}